// Round 4
// baseline (6891.557 us; speedup 1.0000x reference)
//
#include <hip/hip_runtime.h>
#include <math.h>

#define BN_EPS 1e-5f

// Transposed weight layouts: [ci][co][t] (t fastest, co next) so a lane's
// channel slice for one ci is contiguous -> float4 loads.
__device__ __align__(16) float g_wgT[24576];   // gating conv1: [128][64][3]
__device__ __align__(16) float g_we1T[73728];  // expert conv1: [3][128][64][3]
__device__ __align__(16) float g_we2T[18432];  // expert conv2: [3][64][32][3]
__device__ __align__(16) float g_we3T[4608];   // expert conv3: [3][32][16][3]

__global__ __launch_bounds__(256) void transpose_w_kernel(
    const float* __restrict__ gw, const float* __restrict__ e1w,
    const float* __restrict__ e2w, const float* __restrict__ e3w) {
  int idx = blockIdx.x * 256 + threadIdx.x;
  if (idx < 24576) {
    int t = idx % 3, r = idx / 3;
    int co = r & 63, ci = r >> 6;
    g_wgT[idx] = gw[(co * 128 + ci) * 3 + t];
  } else if (idx < 24576 + 73728) {
    int j = idx - 24576;
    int e = j / 24576, jj = j % 24576;
    int t = jj % 3, r = jj / 3;
    int co = r & 63, ci = r >> 6;
    g_we1T[j] = e1w[e * 24576 + (co * 128 + ci) * 3 + t];
  } else if (idx < 24576 + 73728 + 18432) {
    int j = idx - (24576 + 73728);
    int e = j / 6144, jj = j % 6144;
    int t = jj % 3, r = jj / 3;
    int co = r & 31, ci = r >> 5;
    g_we2T[j] = e2w[e * 6144 + (co * 64 + ci) * 3 + t];
  } else if (idx < 24576 + 73728 + 18432 + 4608) {
    int j = idx - (24576 + 73728 + 18432);
    int e = j / 1536, jj = j % 1536;
    int t = jj % 3, r = jj / 3;
    int co = r & 15, ci = r >> 4;
    g_we3T[j] = e3w[e * 1536 + (co * 32 + ci) * 3 + t];
  }
}

// lane = L position. Per ci: 3 scalar LDS reads (stride-1 across lanes,
// conflict-free, no duplication) + NCO*3 FMAs. Weights: per-lane float4
// vector loads, same address wave-wide -> single L1 txn broadcast.
// Keeps the exact fmaf nesting of the previous (bit-exact) kernel.
template <int CIN, int CO, int NCO>
__device__ __forceinline__ void convL(const float* __restrict__ wT,
                                      const float* __restrict__ E, int l,
                                      int cob, float (&acc)[NCO]) {
#pragma unroll 2
  for (int ci = 0; ci < CIN; ++ci) {
    const float* row = E + ci * 64 + l;
    float e0 = row[0], e1 = row[1], e2 = row[2];
    const float4* wp =
        reinterpret_cast<const float4*>(wT + (ci * CO + cob) * 3);
    float w[NCO * 3];
#pragma unroll
    for (int q = 0; q < (NCO * 3) / 4; ++q) {
      float4 v = wp[q];
      w[4 * q + 0] = v.x;
      w[4 * q + 1] = v.y;
      w[4 * q + 2] = v.z;
      w[4 * q + 3] = v.w;
    }
#pragma unroll
    for (int k = 0; k < NCO; ++k)
      acc[k] = fmaf(e0, w[3 * k],
                    fmaf(e1, w[3 * k + 1], fmaf(e2, w[3 * k + 2], acc[k])));
  }
}

__global__ __launch_bounds__(256, 3) void moe_fused_kernel(
    const int* __restrict__ x, const float* __restrict__ embt,
    const float* __restrict__ gcb, const float* __restrict__ gbn,
    const float* __restrict__ gf1w, const float* __restrict__ gf1b,
    const float* __restrict__ gf2w, const float* __restrict__ gf2b,
    const float* __restrict__ e1b, const float* __restrict__ ebn1,
    const float* __restrict__ e2b, const float* __restrict__ ebn2,
    const float* __restrict__ e3b, const float* __restrict__ ebn3,
    const float* __restrict__ f1w, const float* __restrict__ f1b,
    const float* __restrict__ f2w, const float* __restrict__ f2b,
    float* __restrict__ out) {
  // One flat block: deliberate masked-lane overreads stay in-bounds.
  // [0,8192)       Ebuf  [128][64]  (rows 0..31 later reused as C2 [32][64])
  // [8192,12288)   Bbuf  [64][64]   (first reused as Tbuf [60][65] staging)
  // [12288,...)    hbuf64 h2buf32 glog4 mbuf16 o64[64]
  __shared__ __align__(16) float smem[12480];
  float* Ebuf = smem;
  float* Bbuf = smem + 8192;
  float* Tbuf = smem + 8192;  // 60*65 = 3900 <= 4096, dead before Bbuf written
  float* hbuf = smem + 12288;
  float* h2buf = hbuf + 64;
  float* glog = h2buf + 32;
  float* mbuf = glog + 4;
  float* o64 = mbuf + 16;
  __shared__ int toks[60];
  __shared__ int selbuf;

  const int b = blockIdx.x;
  const int tid = threadIdx.x;
  const int lane = tid & 63;
  const int wv = tid >> 6;
  const bool valid = (lane < 60);

  if (tid < 60) toks[tid] = x[b * 60 + tid];
  // zero cols {0,61,62,63} of Ebuf's 128 rows (512 entries, 2 instrs)
  for (int i = tid; i < 512; i += 256) {
    int r = i >> 2;
    const int ctab[4] = {0, 61, 62, 63};
    Ebuf[r * 64 + ctab[i & 3]] = 0.f;
  }
  __syncthreads();

  // ---- emb gather via two-stage transpose (all LDS ops conflict-free) ----
  for (int p = 0; p < 2; ++p) {
    // stage 1: coalesced global read -> Tbuf[l][dp] (stride-1 writes)
    for (int i = tid; i < 60 * 64; i += 256) {
      int l = i >> 6, dp = i & 63;
      Tbuf[l * 65 + dp] = embt[toks[l] * 128 + 64 * p + dp];
    }
    __syncthreads();
    // stage 2: Tbuf (stride-65 reads, conflict-free) -> Ebuf rows (stride-1)
    for (int dp = wv; dp < 64; dp += 4) {
      if (valid) Ebuf[(64 * p + dp) * 64 + lane + 1] = Tbuf[lane * 65 + dp];
    }
    __syncthreads();
  }

  // ---- gating conv1 + BN + ReLU + max over L ----
  {
    float acc[16] = {};
    const int cob = wv * 16;
    convL<128, 64, 16>(g_wgT, Ebuf, lane, cob, acc);
#pragma unroll
    for (int k = 0; k < 16; ++k) {
      int co = cob + k;
      float inv = gbn[co] / sqrtf(gbn[192 + co] + BN_EPS);
      float add = gbn[64 + co] + (gcb[co] - gbn[128 + co]) * inv;
      float v = valid ? fmaxf(fmaf(acc[k], inv, add), 0.f) : -1e30f;
#pragma unroll
      for (int off = 1; off < 64; off <<= 1)
        v = fmaxf(v, __shfl_xor(v, off, 64));
      if (lane == 0) hbuf[co] = v;
    }
  }
  __syncthreads();

  // ---- gating MLP 64->32->3, argmax ----
  if (tid < 32) {
    float a = gf1b[tid];
#pragma unroll 8
    for (int k = 0; k < 64; ++k) a = fmaf(hbuf[k], gf1w[tid * 64 + k], a);
    h2buf[tid] = fmaxf(a, 0.f);
  }
  __syncthreads();
  if (tid < 3) {
    float a = gf2b[tid];
#pragma unroll 8
    for (int k = 0; k < 32; ++k) a = fmaf(h2buf[k], gf2w[tid * 32 + k], a);
    glog[tid] = a;
  }
  __syncthreads();
  if (tid == 0) {
    int best = 0;
    float bv = glog[0];
    if (glog[1] > bv) { bv = glog[1]; best = 1; }
    if (glog[2] > bv) { best = 2; }
    selbuf = best;
  }
  __syncthreads();
  const int e = selbuf;

  // ---- expert conv1 -> Bbuf (BN+ReLU); stride-1 scalar writes ----
  {
    float acc[16] = {};
    const int cob = wv * 16;
    convL<128, 64, 16>(g_we1T + e * 24576, Ebuf, lane, cob, acc);
    const float* bn1 = ebn1 + e * 256;
    const float* cb1 = e1b + e * 64;
#pragma unroll
    for (int k = 0; k < 16; ++k) {
      int co = cob + k;
      float inv = bn1[co] / sqrtf(bn1[192 + co] + BN_EPS);
      float add = bn1[64 + co] + (cb1[co] - bn1[128 + co]) * inv;
      if (valid)
        Bbuf[co * 64 + lane + 1] = fmaxf(fmaf(acc[k], inv, add), 0.f);
    }
  }
  // zero cols {0,61,62,63} of Bbuf's 64 rows (256 entries)
  if (tid < 256) {
    int r = tid >> 2;
    const int ctab[4] = {0, 61, 62, 63};
    Bbuf[r * 64 + ctab[tid & 3]] = 0.f;
  }
  __syncthreads();

  // ---- expert conv2: Bbuf -> C2 (overlays dead Ebuf rows 0..31) ----
  float* C2 = Ebuf;
  {
    float acc[8] = {};
    const int cob = wv * 8;
    convL<64, 32, 8>(g_we2T + e * 6144, Bbuf, lane, cob, acc);
    const float* bn2 = ebn2 + e * 128;
    const float* cb2 = e2b + e * 32;
#pragma unroll
    for (int k = 0; k < 8; ++k) {
      int co = cob + k;
      float inv = bn2[co] / sqrtf(bn2[96 + co] + BN_EPS);
      float add = bn2[32 + co] + (cb2[co] - bn2[64 + co]) * inv;
      if (valid)
        C2[co * 64 + lane + 1] = fmaxf(fmaf(acc[k], inv, add), 0.f);
    }
  }
  // zero cols {0,61,62,63} of C2's 32 rows (128 entries)
  if (tid < 128) {
    int r = tid >> 2;
    const int ctab[4] = {0, 61, 62, 63};
    C2[r * 64 + ctab[tid & 3]] = 0.f;
  }
  __syncthreads();

  // ---- expert conv3 + BN + ReLU + max over L -> mbuf[16] ----
  {
    float acc[4] = {};
    const int cob = wv * 4;
    convL<32, 16, 4>(g_we3T + e * 1536, C2, lane, cob, acc);
    const float* bn3 = ebn3 + e * 64;
    const float* cb3 = e3b + e * 16;
#pragma unroll
    for (int k = 0; k < 4; ++k) {
      int co = cob + k;
      float inv = bn3[co] / sqrtf(bn3[48 + co] + BN_EPS);
      float add = bn3[16 + co] + (cb3[co] - bn3[32 + co]) * inv;
      float v = valid ? fmaxf(fmaf(acc[k], inv, add), 0.f) : -1e30f;
#pragma unroll
      for (int off = 1; off < 64; off <<= 1)
        v = fmaxf(v, __shfl_xor(v, off, 64));
      if (lane == 0) mbuf[co] = v;
    }
  }
  __syncthreads();

  // ---- head MLP 16->64->2 ----
  if (tid < 64) {
    float a = f1b[tid];
#pragma unroll
    for (int k = 0; k < 16; ++k) a = fmaf(mbuf[k], f1w[tid * 16 + k], a);
    o64[tid] = fmaxf(a, 0.f);
  }
  __syncthreads();
  if (tid < 2) {
    float a = f2b[tid];
#pragma unroll 8
    for (int k = 0; k < 64; ++k) a = fmaf(o64[k], f2w[tid * 64 + k], a);
    out[b * 2 + tid] = a;
  }
}

extern "C" void kernel_launch(void* const* d_in, const int* in_sizes, int n_in,
                              void* d_out, int out_size, void* d_ws,
                              size_t ws_size, hipStream_t stream) {
  const int* x = (const int*)d_in[0];
  const float* embt = (const float*)d_in[1];
  const float* gcw = (const float*)d_in[2];
  const float* gcb = (const float*)d_in[3];
  const float* gbn = (const float*)d_in[4];
  const float* gf1w = (const float*)d_in[5];
  const float* gf1b = (const float*)d_in[6];
  const float* gf2w = (const float*)d_in[7];
  const float* gf2b = (const float*)d_in[8];
  const float* e1w = (const float*)d_in[9];
  const float* e1b = (const float*)d_in[10];
  const float* ebn1 = (const float*)d_in[11];
  const float* e2w = (const float*)d_in[12];
  const float* e2b = (const float*)d_in[13];
  const float* ebn2 = (const float*)d_in[14];
  const float* e3w = (const float*)d_in[15];
  const float* e3b = (const float*)d_in[16];
  const float* ebn3 = (const float*)d_in[17];
  const float* f1w = (const float*)d_in[18];
  const float* f1b = (const float*)d_in[19];
  const float* f2w = (const float*)d_in[20];
  const float* f2b = (const float*)d_in[21];
  float* out = (float*)d_out;

  const int B = in_sizes[0] / 60;  // 16384

  transpose_w_kernel<<<(121344 + 255) / 256, 256, 0, stream>>>(gcw, e1w, e2w,
                                                               e3w);
  moe_fused_kernel<<<B, 256, 0, stream>>>(
      x, embt, gcb, gbn, gf1w, gf1b, gf2w, gf2b, e1b, ebn1, e2b, ebn2, e3b,
      ebn3, f1w, f1b, f2w, f2b, out);
}

// Round 5
// 2567.154 us; speedup vs baseline: 2.6845x; 2.6845x over previous
//
#include <hip/hip_runtime.h>
#include <math.h>

#define BN_EPS 1e-5f

// Transposed weight layouts: [ci][co][t] (t fastest, co next) so a wave's
// channel slice for one ci is contiguous. Arrays padded by CO*3 floats so the
// software-pipelined prefetch may overread one ci row safely.
__device__ __align__(16) float g_wgT[24576 + 192];   // gating conv1: [128][64][3]
__device__ __align__(16) float g_we1T[73728 + 192];  // expert conv1: [3][128][64][3]
__device__ __align__(16) float g_we2T[18432 + 96];   // expert conv2: [3][64][32][3]
__device__ __align__(16) float g_we3T[4608 + 48];    // expert conv3: [3][32][16][3]

__global__ __launch_bounds__(256) void transpose_w_kernel(
    const float* __restrict__ gw, const float* __restrict__ e1w,
    const float* __restrict__ e2w, const float* __restrict__ e3w) {
  int idx = blockIdx.x * 256 + threadIdx.x;
  if (idx < 24576) {
    int t = idx % 3, r = idx / 3;
    int co = r & 63, ci = r >> 6;
    g_wgT[idx] = gw[(co * 128 + ci) * 3 + t];
  } else if (idx < 24576 + 73728) {
    int j = idx - 24576;
    int e = j / 24576, jj = j % 24576;
    int t = jj % 3, r = jj / 3;
    int co = r & 63, ci = r >> 6;
    g_we1T[j] = e1w[e * 24576 + (co * 128 + ci) * 3 + t];
  } else if (idx < 24576 + 73728 + 18432) {
    int j = idx - (24576 + 73728);
    int e = j / 6144, jj = j % 6144;
    int t = jj % 3, r = jj / 3;
    int co = r & 31, ci = r >> 5;
    g_we2T[j] = e2w[e * 6144 + (co * 64 + ci) * 3 + t];
  } else if (idx < 24576 + 73728 + 18432 + 4608) {
    int j = idx - (24576 + 73728 + 18432);
    int e = j / 1536, jj = j % 1536;
    int t = jj % 3, r = jj / 3;
    int co = r & 15, ci = r >> 4;
    g_we3T[j] = e3w[e * 1536 + (co * 32 + ci) * 3 + t];
  }
}

// lane = L position. Per ci: 3 scalar LDS reads (stride-1 across lanes,
// conflict-free, zero duplication) + NCO*3 FMAs. Weight loads are
// wave-uniform-address (cob uniform) and manually double-buffered (ping-pong
// wa/wb) so the load of ci+1 is in flight during the FMAs of ci.
// Exact fmaf nesting preserved (bit-identical output across rounds).
template <int CIN, int CO, int NCO>
__device__ __forceinline__ void convL(const float* __restrict__ wT,
                                      const float* E, int l, int cob,
                                      float (&acc)[NCO]) {
  constexpr int NW = (NCO * 3) / 4;
  float4 wa[NW], wb[NW];
  {
    const float4* wp = reinterpret_cast<const float4*>(wT + cob * 3);
#pragma unroll
    for (int q = 0; q < NW; ++q) wa[q] = wp[q];
  }
#pragma unroll 2
  for (int ci = 0; ci < CIN; ci += 2) {
    {
      const float4* wp =
          reinterpret_cast<const float4*>(wT + ((ci + 1) * CO + cob) * 3);
#pragma unroll
      for (int q = 0; q < NW; ++q) wb[q] = wp[q];
    }
    {
      const float* row = E + ci * 64 + l;
      float e0 = row[0], e1 = row[1], e2 = row[2];
      const float* w = reinterpret_cast<const float*>(wa);
#pragma unroll
      for (int k = 0; k < NCO; ++k)
        acc[k] = fmaf(e0, w[3 * k],
                      fmaf(e1, w[3 * k + 1], fmaf(e2, w[3 * k + 2], acc[k])));
    }
    {
      const float4* wp =
          reinterpret_cast<const float4*>(wT + ((ci + 2) * CO + cob) * 3);
#pragma unroll
      for (int q = 0; q < NW; ++q) wa[q] = wp[q];  // overreads pad at ci+2==CIN
    }
    {
      const float* row = E + (ci + 1) * 64 + l;
      float e0 = row[0], e1 = row[1], e2 = row[2];
      const float* w = reinterpret_cast<const float*>(wb);
#pragma unroll
      for (int k = 0; k < NCO; ++k)
        acc[k] = fmaf(e0, w[3 * k],
                      fmaf(e1, w[3 * k + 1], fmaf(e2, w[3 * k + 2], acc[k])));
    }
  }
}

__global__ __launch_bounds__(256, 3) void moe_fused_kernel(
    const int* __restrict__ x, const float* __restrict__ embt,
    const float* __restrict__ gcb, const float* __restrict__ gbn,
    const float* __restrict__ gf1w, const float* __restrict__ gf1b,
    const float* __restrict__ gf2w, const float* __restrict__ gf2b,
    const float* __restrict__ e1b, const float* __restrict__ ebn1,
    const float* __restrict__ e2b, const float* __restrict__ ebn2,
    const float* __restrict__ e3b, const float* __restrict__ ebn3,
    const float* __restrict__ f1w, const float* __restrict__ f1b,
    const float* __restrict__ f2w, const float* __restrict__ f2b,
    float* __restrict__ out) {
  // One flat block: deliberate masked-lane overreads stay in-bounds.
  // [0,8192)       Ebuf  [128][64]  (rows 0..31 later reused as C2 [32][64])
  // [8192,12288)   Bbuf  [64][64]   (first reused as Tbuf [60][65] staging)
  // [12288,...)    hbuf64 h2buf32 glog4 mbuf16 o64[64]
  __shared__ __align__(16) float smem[12480];
  float* Ebuf = smem;
  float* Bbuf = smem + 8192;
  float* Tbuf = smem + 8192;  // 60*65 = 3900 <= 4096, dead before Bbuf written
  float* hbuf = smem + 12288;
  float* h2buf = hbuf + 64;
  float* glog = h2buf + 32;
  float* mbuf = glog + 4;
  float* o64 = mbuf + 16;
  __shared__ int toks[60];
  __shared__ int selbuf;

  const int b = blockIdx.x;
  const int tid = threadIdx.x;
  const int lane = tid & 63;
  const int wv = tid >> 6;
  const int wvu = __builtin_amdgcn_readfirstlane(wv);  // provably uniform
  const bool valid = (lane < 60);

  if (tid < 60) toks[tid] = x[b * 60 + tid];
  // zero cols {0,61,62,63} of Ebuf's 128 rows (512 entries, 2 instrs)
  for (int i = tid; i < 512; i += 256) {
    int r = i >> 2;
    const int ctab[4] = {0, 61, 62, 63};
    Ebuf[r * 64 + ctab[i & 3]] = 0.f;
  }
  __syncthreads();

  // ---- emb gather via two-stage transpose (all LDS ops conflict-free) ----
  for (int p = 0; p < 2; ++p) {
    // stage 1: coalesced global read -> Tbuf[l][dp] (stride-1 writes)
    for (int i = tid; i < 60 * 64; i += 256) {
      int l = i >> 6, dp = i & 63;
      Tbuf[l * 65 + dp] = embt[toks[l] * 128 + 64 * p + dp];
    }
    __syncthreads();
    // stage 2: Tbuf (stride-65 reads, conflict-free) -> Ebuf rows (stride-1)
    for (int dp = wv; dp < 64; dp += 4) {
      if (valid) Ebuf[(64 * p + dp) * 64 + lane + 1] = Tbuf[lane * 65 + dp];
    }
    __syncthreads();
  }

  // ---- gating conv1 + BN + ReLU + max over L ----
  {
    float acc[16] = {};
    const int cob = wvu * 16;
    convL<128, 64, 16>(g_wgT, Ebuf, lane, cob, acc);
#pragma unroll
    for (int k = 0; k < 16; ++k) {
      int co = cob + k;
      float inv = gbn[co] / sqrtf(gbn[192 + co] + BN_EPS);
      float add = gbn[64 + co] + (gcb[co] - gbn[128 + co]) * inv;
      float v = valid ? fmaxf(fmaf(acc[k], inv, add), 0.f) : -1e30f;
#pragma unroll
      for (int off = 1; off < 64; off <<= 1)
        v = fmaxf(v, __shfl_xor(v, off, 64));
      if (lane == 0) hbuf[co] = v;
    }
  }
  __syncthreads();

  // ---- gating MLP 64->32->3, argmax ----
  if (tid < 32) {
    float a = gf1b[tid];
#pragma unroll 8
    for (int k = 0; k < 64; ++k) a = fmaf(hbuf[k], gf1w[tid * 64 + k], a);
    h2buf[tid] = fmaxf(a, 0.f);
  }
  __syncthreads();
  if (tid < 3) {
    float a = gf2b[tid];
#pragma unroll 8
    for (int k = 0; k < 32; ++k) a = fmaf(h2buf[k], gf2w[tid * 32 + k], a);
    glog[tid] = a;
  }
  __syncthreads();
  if (tid == 0) {
    int best = 0;
    float bv = glog[0];
    if (glog[1] > bv) { bv = glog[1]; best = 1; }
    if (glog[2] > bv) { best = 2; }
    selbuf = best;
  }
  __syncthreads();
  const int e = __builtin_amdgcn_readfirstlane(selbuf);  // uniform expert id

  // ---- expert conv1 -> Bbuf (BN+ReLU); stride-1 scalar writes ----
  {
    float acc[16] = {};
    const int cob = wvu * 16;
    convL<128, 64, 16>(g_we1T + e * 24576, Ebuf, lane, cob, acc);
    const float* bn1 = ebn1 + e * 256;
    const float* cb1 = e1b + e * 64;
#pragma unroll
    for (int k = 0; k < 16; ++k) {
      int co = cob + k;
      float inv = bn1[co] / sqrtf(bn1[192 + co] + BN_EPS);
      float add = bn1[64 + co] + (cb1[co] - bn1[128 + co]) * inv;
      if (valid)
        Bbuf[co * 64 + lane + 1] = fmaxf(fmaf(acc[k], inv, add), 0.f);
    }
  }
  // zero cols {0,61,62,63} of Bbuf's 64 rows (256 entries)
  {
    int r = tid >> 2;
    const int ctab[4] = {0, 61, 62, 63};
    Bbuf[r * 64 + ctab[tid & 3]] = 0.f;
  }
  __syncthreads();

  // ---- expert conv2: Bbuf -> C2 (overlays dead Ebuf rows 0..31) ----
  float* C2 = Ebuf;
  {
    float acc[8] = {};
    const int cob = wvu * 8;
    convL<64, 32, 8>(g_we2T + e * 6144, Bbuf, lane, cob, acc);
    const float* bn2 = ebn2 + e * 128;
    const float* cb2 = e2b + e * 32;
#pragma unroll
    for (int k = 0; k < 8; ++k) {
      int co = cob + k;
      float inv = bn2[co] / sqrtf(bn2[96 + co] + BN_EPS);
      float add = bn2[32 + co] + (cb2[co] - bn2[64 + co]) * inv;
      if (valid)
        C2[co * 64 + lane + 1] = fmaxf(fmaf(acc[k], inv, add), 0.f);
    }
  }
  // zero cols {0,61,62,63} of C2's 32 rows (128 entries)
  if (tid < 128) {
    int r = tid >> 2;
    const int ctab[4] = {0, 61, 62, 63};
    C2[r * 64 + ctab[tid & 3]] = 0.f;
  }
  __syncthreads();

  // ---- expert conv3 + BN + ReLU + max over L -> mbuf[16] ----
  {
    float acc[4] = {};
    const int cob = wvu * 4;
    convL<32, 16, 4>(g_we3T + e * 1536, C2, lane, cob, acc);
    const float* bn3 = ebn3 + e * 64;
    const float* cb3 = e3b + e * 16;
#pragma unroll
    for (int k = 0; k < 4; ++k) {
      int co = cob + k;
      float inv = bn3[co] / sqrtf(bn3[48 + co] + BN_EPS);
      float add = bn3[16 + co] + (cb3[co] - bn3[32 + co]) * inv;
      float v = valid ? fmaxf(fmaf(acc[k], inv, add), 0.f) : -1e30f;
#pragma unroll
      for (int off = 1; off < 64; off <<= 1)
        v = fmaxf(v, __shfl_xor(v, off, 64));
      if (lane == 0) mbuf[co] = v;
    }
  }
  __syncthreads();

  // ---- head MLP 16->64->2 ----
  if (tid < 64) {
    float a = f1b[tid];
#pragma unroll
    for (int k = 0; k < 16; ++k) a = fmaf(mbuf[k], f1w[tid * 16 + k], a);
    o64[tid] = fmaxf(a, 0.f);
  }
  __syncthreads();
  if (tid < 2) {
    float a = f2b[tid];
#pragma unroll 8
    for (int k = 0; k < 64; ++k) a = fmaf(o64[k], f2w[tid * 64 + k], a);
    out[b * 2 + tid] = a;
  }
}

extern "C" void kernel_launch(void* const* d_in, const int* in_sizes, int n_in,
                              void* d_out, int out_size, void* d_ws,
                              size_t ws_size, hipStream_t stream) {
  const int* x = (const int*)d_in[0];
  const float* embt = (const float*)d_in[1];
  const float* gcw = (const float*)d_in[2];
  const float* gcb = (const float*)d_in[3];
  const float* gbn = (const float*)d_in[4];
  const float* gf1w = (const float*)d_in[5];
  const float* gf1b = (const float*)d_in[6];
  const float* gf2w = (const float*)d_in[7];
  const float* gf2b = (const float*)d_in[8];
  const float* e1w = (const float*)d_in[9];
  const float* e1b = (const float*)d_in[10];
  const float* ebn1 = (const float*)d_in[11];
  const float* e2w = (const float*)d_in[12];
  const float* e2b = (const float*)d_in[13];
  const float* ebn2 = (const float*)d_in[14];
  const float* e3w = (const float*)d_in[15];
  const float* e3b = (const float*)d_in[16];
  const float* ebn3 = (const float*)d_in[17];
  const float* f1w = (const float*)d_in[18];
  const float* f1b = (const float*)d_in[19];
  const float* f2w = (const float*)d_in[20];
  const float* f2b = (const float*)d_in[21];
  float* out = (float*)d_out;

  const int B = in_sizes[0] / 60;  // 16384

  transpose_w_kernel<<<(121344 + 255) / 256, 256, 0, stream>>>(gcw, e1w, e2w,
                                                               e3w);
  moe_fused_kernel<<<B, 256, 0, stream>>>(
      x, embt, gcb, gbn, gf1w, gf1b, gf2w, gf2b, e1b, ebn1, e2b, ebn2, e3b,
      ebn3, f1w, f1b, f2w, f2b, out);
}

// Round 6
// 1398.692 us; speedup vs baseline: 4.9271x; 1.8354x over previous
//
#include <hip/hip_runtime.h>
#include <math.h>

#define BN_EPS 1e-5f

typedef float v2f __attribute__((ext_vector_type(2)));

// Weight layout [ci][t][co] (co fastest) -> channel pairs contiguous ->
// v_pk_fma_f32. Padded by one ci row (3*CO) for pipelined overread.
__device__ __align__(16) float g_wgT[24576 + 192];   // gating conv1 [128][3][64]
__device__ __align__(16) float g_we1T[73728 + 192];  // expert conv1 [3][128][3][64]
__device__ __align__(16) float g_we2T[18432 + 96];   // expert conv2 [3][64][3][32]
__device__ __align__(16) float g_we3T[4608 + 48];    // expert conv3 [3][32][3][16]

__global__ __launch_bounds__(256) void transpose_w_kernel(
    const float* __restrict__ gw, const float* __restrict__ e1w,
    const float* __restrict__ e2w, const float* __restrict__ e3w) {
  int idx = blockIdx.x * 256 + threadIdx.x;
  if (idx < 24576) {
    int co = idx & 63, r = idx >> 6;
    int t = r % 3, ci = r / 3;
    g_wgT[idx] = gw[(co * 128 + ci) * 3 + t];
  } else if (idx < 24576 + 73728) {
    int j = idx - 24576;
    int e = j / 24576, jj = j % 24576;
    int co = jj & 63, r = jj >> 6;
    int t = r % 3, ci = r / 3;
    g_we1T[j] = e1w[e * 24576 + (co * 128 + ci) * 3 + t];
  } else if (idx < 24576 + 73728 + 18432) {
    int j = idx - (24576 + 73728);
    int e = j / 6144, jj = j % 6144;
    int co = jj & 31, r = jj >> 5;
    int t = r % 3, ci = r / 3;
    g_we2T[j] = e2w[e * 6144 + (co * 64 + ci) * 3 + t];
  } else if (idx < 24576 + 73728 + 18432 + 4608) {
    int j = idx - (24576 + 73728 + 18432);
    int e = j / 1536, jj = j % 1536;
    int co = jj & 15, r = jj >> 4;
    int t = r % 3, ci = r / 3;
    g_we3T[j] = e3w[e * 1536 + (co * 32 + ci) * 3 + t];
  }
}

// lane = L position. Per ci: 3 scalar LDS reads (stride-1, conflict-free) +
// NCO*3 FMAs as NCO/2*3 packed v_pk_fma_f32. wT pre-offset by cob; t-block at
// ci*3*CO + t*CO. Per-channel fmaf chain (t descending) preserved exactly ->
// bit-identical to previous rounds. acc may carry across calls (ci tiling).
template <int CIN, int CO, int NCO>
__device__ __forceinline__ void convPK(const float* __restrict__ wT,
                                       const float* E, int l,
                                       v2f (&acc)[NCO / 2]) {
  constexpr int NW = (NCO * 3) / 4;
  constexpr int N4 = NCO / 4;
  float4 wa[NW], wb[NW];
  auto loadci = [&](int ci, float4(&w)[NW]) {
#pragma unroll
    for (int t = 0; t < 3; ++t) {
      const float4* p =
          reinterpret_cast<const float4*>(wT + ci * (3 * CO) + t * CO);
#pragma unroll
      for (int q = 0; q < N4; ++q) w[t * N4 + q] = p[q];
    }
  };
  auto fmaci = [&](int ci, const float4(&w4)[NW]) {
    const float* row = E + ci * 64 + l;
    float e0 = row[0], e1 = row[1], e2 = row[2];
    v2f e0v = {e0, e0}, e1v = {e1, e1}, e2v = {e2, e2};
    const v2f* w = reinterpret_cast<const v2f*>(w4);
#pragma unroll
    for (int k2 = 0; k2 < NCO / 2; ++k2)
      acc[k2] = __builtin_elementwise_fma(
          e0v, w[0 * (NCO / 2) + k2],
          __builtin_elementwise_fma(
              e1v, w[1 * (NCO / 2) + k2],
              __builtin_elementwise_fma(e2v, w[2 * (NCO / 2) + k2], acc[k2])));
  };
  loadci(0, wa);
#pragma unroll 2
  for (int ci = 0; ci < CIN; ci += 2) {
    loadci(ci + 1, wb);
    fmaci(ci, wa);
    loadci(ci + 2, wa);  // overreads pad row at ci+2==CIN (in-bounds)
    fmaci(ci + 1, wb);
  }
}

__global__ __launch_bounds__(256, 6) void moe_fused_kernel(
    const int* __restrict__ x, const float* __restrict__ embt,
    const float* __restrict__ gcb, const float* __restrict__ gbn,
    const float* __restrict__ gf1w, const float* __restrict__ gf1b,
    const float* __restrict__ gf2w, const float* __restrict__ gf2b,
    const float* __restrict__ e1b, const float* __restrict__ ebn1,
    const float* __restrict__ e2b, const float* __restrict__ ebn2,
    const float* __restrict__ e3b, const float* __restrict__ ebn3,
    const float* __restrict__ f1w, const float* __restrict__ f1b,
    const float* __restrict__ f2w, const float* __restrict__ f2b,
    float* __restrict__ out) {
  // Flat smem (deliberate masked-lane overreads stay in-bounds):
  // [0,2048)      tileE [32][64]  (later reused as C2 [32][64])
  // [2048,6144)   Bbuf  [64][64]  (reused as Tbuf [60][33] during gathers)
  // [6144,6324)   hbuf64 h2buf32 glog4 mbuf16 o64
  __shared__ __align__(16) float smem[6400];
  float* tileE = smem;
  float* Bbuf = smem + 2048;
  float* Tbuf = smem + 2048;  // alias: dead whenever Bbuf data is live
  float* hbuf = smem + 6144;
  float* h2buf = hbuf + 64;
  float* glog = h2buf + 32;
  float* mbuf = glog + 4;
  float* o64 = mbuf + 16;
  __shared__ int toks[60];
  __shared__ int selbuf;

  const int b = blockIdx.x;
  const int tid = threadIdx.x;
  const int lane = tid & 63;
  const int wv = tid >> 6;
  const int wvu = __builtin_amdgcn_readfirstlane(wv);
  const bool valid = (lane < 60);

  if (tid < 60) toks[tid] = x[b * 60 + tid];
  // zero tileE pad cols {0,61,62,63} once; stage2 never touches them and
  // conv2's C2 writes don't either -> stay zero for conv1 tiles AND conv3.
  if (tid < 128) {
    int r = tid >> 2;
    const int ctab[4] = {0, 61, 62, 63};
    tileE[r * 64 + ctab[tid & 3]] = 0.f;
  }
  __syncthreads();

  // gather one 32-d tile of emb into tileE via two-stage transpose
  auto gather_tile = [&](int tile) {
    for (int i = tid; i < 60 * 32; i += 256) {  // coalesced; table is L1-hot
      int l = i >> 5, dp = i & 31;
      Tbuf[l * 33 + dp] = embt[toks[l] * 128 + tile * 32 + dp];
    }
    __syncthreads();
    if (valid) {
#pragma unroll
      for (int dp = wvu; dp < 32; dp += 4)
        tileE[dp * 64 + lane + 1] = Tbuf[lane * 33 + dp];
    }
    __syncthreads();
  };

  // ---- gating conv1 (tiled over ci) + BN + ReLU + max over L ----
  {
    v2f acc[8] = {};
    const int cob = wvu * 16;
    for (int tile = 0; tile < 4; ++tile) {
      gather_tile(tile);
      convPK<32, 64, 16>(g_wgT + tile * 32 * 192 + cob, tileE, lane, acc);
      __syncthreads();
    }
#pragma unroll
    for (int k = 0; k < 16; ++k) {
      int co = cob + k;
      float inv = gbn[co] / sqrtf(gbn[192 + co] + BN_EPS);
      float add = gbn[64 + co] + (gcb[co] - gbn[128 + co]) * inv;
      float v = valid ? fmaxf(fmaf(acc[k >> 1][k & 1], inv, add), 0.f) : -1e30f;
#pragma unroll
      for (int off = 1; off < 64; off <<= 1)
        v = fmaxf(v, __shfl_xor(v, off, 64));
      if (lane == 0) hbuf[co] = v;
    }
  }
  __syncthreads();

  // ---- gating MLP 64->32->3, argmax ----
  if (tid < 32) {
    float a = gf1b[tid];
#pragma unroll 8
    for (int k = 0; k < 64; ++k) a = fmaf(hbuf[k], gf1w[tid * 64 + k], a);
    h2buf[tid] = fmaxf(a, 0.f);
  }
  __syncthreads();
  if (tid < 3) {
    float a = gf2b[tid];
#pragma unroll 8
    for (int k = 0; k < 32; ++k) a = fmaf(h2buf[k], gf2w[tid * 32 + k], a);
    glog[tid] = a;
  }
  __syncthreads();
  if (tid == 0) {
    int best = 0;
    float bv = glog[0];
    if (glog[1] > bv) { bv = glog[1]; best = 1; }
    if (glog[2] > bv) { best = 2; }
    selbuf = best;
  }
  __syncthreads();
  const int e = __builtin_amdgcn_readfirstlane(selbuf);

  // ---- expert conv1 (re-gather tiles) -> Bbuf (BN+ReLU) ----
  {
    v2f acc[8] = {};
    const int cob = wvu * 16;
    for (int tile = 0; tile < 4; ++tile) {
      gather_tile(tile);
      convPK<32, 64, 16>(g_we1T + e * 24576 + tile * 32 * 192 + cob, tileE,
                         lane, acc);
      __syncthreads();
    }
    const float* bn1 = ebn1 + e * 256;
    const float* cb1 = e1b + e * 64;
#pragma unroll
    for (int k = 0; k < 16; ++k) {
      int co = cob + k;
      float inv = bn1[co] / sqrtf(bn1[192 + co] + BN_EPS);
      float add = bn1[64 + co] + (cb1[co] - bn1[128 + co]) * inv;
      if (valid)
        Bbuf[co * 64 + lane + 1] =
            fmaxf(fmaf(acc[k >> 1][k & 1], inv, add), 0.f);
    }
  }
  // zero Bbuf pad cols (Tbuf aliasing dirtied them)
  {
    int r = tid >> 2;
    const int ctab[4] = {0, 61, 62, 63};
    Bbuf[r * 64 + ctab[tid & 3]] = 0.f;
  }
  __syncthreads();

  // ---- expert conv2: Bbuf -> C2 (overlays tileE) ----
  float* C2 = tileE;
  {
    v2f acc[4] = {};
    const int cob = wvu * 8;
    convPK<64, 32, 8>(g_we2T + e * 6144 + cob, Bbuf, lane, acc);
    const float* bn2 = ebn2 + e * 128;
    const float* cb2 = e2b + e * 32;
#pragma unroll
    for (int k = 0; k < 8; ++k) {
      int co = cob + k;
      float inv = bn2[co] / sqrtf(bn2[96 + co] + BN_EPS);
      float add = bn2[32 + co] + (cb2[co] - bn2[64 + co]) * inv;
      if (valid)
        C2[co * 64 + lane + 1] =
            fmaxf(fmaf(acc[k >> 1][k & 1], inv, add), 0.f);
    }
  }
  __syncthreads();

  // ---- expert conv3 + BN + ReLU + max over L -> mbuf[16] ----
  {
    v2f acc[2] = {};
    const int cob = wvu * 4;
    convPK<32, 16, 4>(g_we3T + e * 1536 + cob, C2, lane, acc);
    const float* bn3 = ebn3 + e * 64;
    const float* cb3 = e3b + e * 16;
#pragma unroll
    for (int k = 0; k < 4; ++k) {
      int co = cob + k;
      float inv = bn3[co] / sqrtf(bn3[48 + co] + BN_EPS);
      float add = bn3[16 + co] + (cb3[co] - bn3[32 + co]) * inv;
      float v = valid ? fmaxf(fmaf(acc[k >> 1][k & 1], inv, add), 0.f) : -1e30f;
#pragma unroll
      for (int off = 1; off < 64; off <<= 1)
        v = fmaxf(v, __shfl_xor(v, off, 64));
      if (lane == 0) mbuf[co] = v;
    }
  }
  __syncthreads();

  // ---- head MLP 16->64->2 ----
  if (tid < 64) {
    float a = f1b[tid];
#pragma unroll
    for (int k = 0; k < 16; ++k) a = fmaf(mbuf[k], f1w[tid * 16 + k], a);
    o64[tid] = fmaxf(a, 0.f);
  }
  __syncthreads();
  if (tid < 2) {
    float a = f2b[tid];
#pragma unroll 8
    for (int k = 0; k < 64; ++k) a = fmaf(o64[k], f2w[tid * 64 + k], a);
    out[b * 2 + tid] = a;
  }
}

extern "C" void kernel_launch(void* const* d_in, const int* in_sizes, int n_in,
                              void* d_out, int out_size, void* d_ws,
                              size_t ws_size, hipStream_t stream) {
  const int* x = (const int*)d_in[0];
  const float* embt = (const float*)d_in[1];
  const float* gcw = (const float*)d_in[2];
  const float* gcb = (const float*)d_in[3];
  const float* gbn = (const float*)d_in[4];
  const float* gf1w = (const float*)d_in[5];
  const float* gf1b = (const float*)d_in[6];
  const float* gf2w = (const float*)d_in[7];
  const float* gf2b = (const float*)d_in[8];
  const float* e1w = (const float*)d_in[9];
  const float* e1b = (const float*)d_in[10];
  const float* ebn1 = (const float*)d_in[11];
  const float* e2w = (const float*)d_in[12];
  const float* e2b = (const float*)d_in[13];
  const float* ebn2 = (const float*)d_in[14];
  const float* e3w = (const float*)d_in[15];
  const float* e3b = (const float*)d_in[16];
  const float* ebn3 = (const float*)d_in[17];
  const float* f1w = (const float*)d_in[18];
  const float* f1b = (const float*)d_in[19];
  const float* f2w = (const float*)d_in[20];
  const float* f2b = (const float*)d_in[21];
  float* out = (float*)d_out;

  const int B = in_sizes[0] / 60;  // 16384

  transpose_w_kernel<<<(121344 + 255) / 256, 256, 0, stream>>>(gcw, e1w, e2w,
                                                               e3w);
  moe_fused_kernel<<<B, 256, 0, stream>>>(
      x, embt, gcb, gbn, gf1w, gf1b, gf2w, gf2b, e1b, ebn1, e2b, ebn2, e3b,
      ebn3, f1w, f1b, f2w, f2b, out);
}